// Round 8
// baseline (179.986 us; speedup 1.0000x reference)
//
#include <hip/hip_runtime.h>

#define EPS 1e-5f
#define LOG2E 1.4426950408889634f

typedef short v8s __attribute__((ext_vector_type(8)));
typedef float v4f __attribute__((ext_vector_type(4)));

// RNE f32->bf16 pair pack: single instruction, HW-verified pattern (learn_hip m240/T12)
__device__ inline unsigned cvt_pk_bf16(float a, float b) {
    unsigned r;
    asm("v_cvt_pk_bf16_f32 %0, %1, %2" : "=v"(r) : "v"(a), "v"(b));
    return r;
}
__device__ inline unsigned short f2bf(float f) {
    return (unsigned short)cvt_pk_bf16(f, f);
}
__device__ inline float bf2f(unsigned short u) {
    union { unsigned u; float f; } v; v.u = (unsigned)u << 16;
    return v.f;
}

// LDS map (32,256 B):
//   [0      ..  6144)  Qb  ushort[32][96]  Q~ bf16 rows g*4+c (pre-scaled by simA*log2e)
//   [6144   .. 18432)  Kf  float[32][96]   K fp32 rows g*4+c
//   [18432  .. 31744)  Vb  ushort[64][104] V bf16 rows g*8+c
//   phase-1 overlay: Xb ushort[96][72] @0, Wb ushort[128][72] @13824 (dead before epilogue)
//
// R8: single-kernel DIRECT write. Output line (128B) = out[nt][cl][dd][hs..hs+31]
// is filled by 32 hs-consecutive blocks. Dispatch assigns xcd = bid%8 (T1/m157
// model), so we remap bid -> (nt, hs) such that each aligned 32-hs chunk runs
// entirely on ONE XCD: its L2 accumulates all 32 scalar writes per line and
// evicts full lines (no cross-XCD partial-line RMW storm). Any bijection is
// correctness-safe; the mapping is performance-only.
// NOTE: __launch_bounds__ min-waves/EU must stay <=3: (256,5) forced VGPR<=102
// and miscompiled/spilled (R5/R6 corruption, bisected in R7).
__global__ __launch_bounds__(256, 3) void attn_kernel(
    const float* __restrict__ x,
    const float* __restrict__ w,
    const float* __restrict__ qkv_gamma, const float* __restrict__ qkv_beta,
    const float* __restrict__ qkv_mean,  const float* __restrict__ qkv_var,
    const float* __restrict__ sim_gamma, const float* __restrict__ sim_beta,
    const float* __restrict__ sim_mean,  const float* __restrict__ sim_var,
    const float* __restrict__ out_gamma, const float* __restrict__ out_beta,
    const float* __restrict__ out_mean,  const float* __restrict__ out_var,
    float* __restrict__ dst)
{
    __shared__ __align__(16) unsigned char smem[32256];
    unsigned short (*Qb)[96]  = (unsigned short(*)[96])smem;
    float (*Kf)[96]           = (float(*)[96])(smem + 6144);
    unsigned short (*Vb)[104] = (unsigned short(*)[104])(smem + 18432);
    unsigned short (*Xb)[72]  = (unsigned short(*)[72])smem;
    unsigned short (*Wb)[72]  = (unsigned short(*)[72])(smem + 13824);

    const int tid  = threadIdx.x;
    const int lane = tid & 63;
    const int wid  = tid >> 6;
    const int quad = lane >> 4;

    // XCD-chunked (nt, hs) assignment: 64 chunks of 32 hs-consecutive blocks,
    // each chunk pinned to one XCD via the bid%8 dispatch model.
    const int bid = blockIdx.x;
    const int xcd = bid & 7;
    const int ixc = bid >> 3;           // index on this XCD, 0..255
    const int con = ixc >> 5;           // chunk slot on this XCD, 0..7
    const int wch = ixc & 31;           // block within chunk
    const int gch = con * 8 + xcd;      // global chunk id, 0..63
    const int nt  = gch >> 1;
    const int hs  = ((gch & 1) << 5) + wch;

    const float* xb = x + (size_t)nt * 393216 + (size_t)hs * 64;
    const float4* x4 = reinterpret_cast<const float4*>(xb);
    const float4* w4 = reinterpret_cast<const float4*>(w);

    // ---------------- Phase 1a: stage X, W as bf16 ----------------
    #pragma unroll
    for (int it = 0; it < 6; ++it) {
        int idx = tid + it * 256;               // 1536 float4s
        int cl = idx >> 4, v = idx & 15;
        float4 val = x4[cl * 1024 + v];
        unsigned* dx = (unsigned*)&Xb[cl][v * 4];
        dx[0] = cvt_pk_bf16(val.x, val.y);
        dx[1] = cvt_pk_bf16(val.z, val.w);
    }
    #pragma unroll
    for (int it = 0; it < 8; ++it) {
        int idx = tid + it * 256;               // 2048 float4s
        int r = idx >> 4, v = idx & 15;
        float4 val = w4[r * 16 + v];
        unsigned* dw = (unsigned*)&Wb[r][v * 4];
        dw[0] = cvt_pk_bf16(val.x, val.y);
        dw[1] = cvt_pk_bf16(val.z, val.w);
    }
    __syncthreads();

    // ---------------- Phase 1b: QKV = W @ X via MFMA ----------------
    v4f acc1[2][6];
    #pragma unroll
    for (int mi = 0; mi < 2; ++mi)
        #pragma unroll
        for (int ni = 0; ni < 6; ++ni) acc1[mi][ni] = (v4f)(0.f);

    #pragma unroll
    for (int kt = 0; kt < 2; ++kt) {
        v8s a0 = *reinterpret_cast<const v8s*>(&Wb[(wid * 2 + 0) * 16 + (lane & 15)][kt * 32 + quad * 8]);
        v8s a1 = *reinterpret_cast<const v8s*>(&Wb[(wid * 2 + 1) * 16 + (lane & 15)][kt * 32 + quad * 8]);
        #pragma unroll
        for (int ni = 0; ni < 6; ++ni) {
            v8s bfr = *reinterpret_cast<const v8s*>(&Xb[ni * 16 + (lane & 15)][kt * 32 + quad * 8]);
            acc1[0][ni] = __builtin_amdgcn_mfma_f32_16x16x32_bf16(a0, bfr, acc1[0][ni], 0, 0, 0);
            acc1[1][ni] = __builtin_amdgcn_mfma_f32_16x16x32_bf16(a1, bfr, acc1[1][ni], 0, 0, 0);
        }
    }
    __syncthreads();    // staging dead; region becomes Qb/Kf/Vb (last barrier in kernel)

    // epilogue: BN; rows r<4 -> Qb bf16 (scaled by simA*log2e); 4<=r<8 -> Kf fp32; r>=8 -> Vb bf16
    #pragma unroll
    for (int mi = 0; mi < 2; ++mi) {
        const int mt = wid * 2 + mi;            // = group g
        const float sA = sim_gamma[mt] * rsqrtf(sim_var[mt] + EPS) * LOG2E;
        #pragma unroll
        for (int reg = 0; reg < 4; ++reg) {
            int o = mt * 16 + quad * 4 + reg;
            int r = o & 15;
            float sc = qkv_gamma[o] * rsqrtf(qkv_var[o] + EPS);
            float mb = qkv_beta[o] - qkv_mean[o] * sc;
            if (r < 4) { sc *= sA; mb *= sA; }
            if (r < 4) {
                #pragma unroll
                for (int ni = 0; ni < 6; ++ni)
                    Qb[mt * 4 + r][ni * 16 + (lane & 15)] = f2bf(acc1[mi][ni][reg] * sc + mb);
            } else if (r < 8) {
                #pragma unroll
                for (int ni = 0; ni < 6; ++ni)
                    Kf[mt * 4 + (r - 4)][ni * 16 + (lane & 15)] = acc1[mi][ni][reg] * sc + mb;
            } else {
                #pragma unroll
                for (int ni = 0; ni < 6; ++ni)
                    Vb[mt * 8 + (r - 8)][ni * 16 + (lane & 15)] = f2bf(acc1[mi][ni][reg] * sc + mb);
            }
        }
    }
    // NO barrier: each wave consumes only rows it just wrote.

    // ---------------- Phase 2: wave-private groups, P in registers ----------------
    const int r15 = lane & 15;

    for (int gi = 0; gi < 2; ++gi) {
        const int g = wid * 2 + gi;

        // q preload: 24 broadcast u16 reads + shift
        float qv[4][6];
        #pragma unroll
        for (int c = 0; c < 4; ++c)
            #pragma unroll
            for (int mt = 0; mt < 6; ++mt)
                qv[c][mt] = bf2f(Qb[g * 4 + c][mt * 16 + r15]);

        v4f acc[6];
        v4f rs4[6];
        #pragma unroll
        for (int mt = 0; mt < 6; ++mt) { acc[mt] = (v4f)(0.f); rs4[mt] = (v4f)(0.f); }

        const float* kbase = &Kf[g * 4][quad * 8];
        const unsigned short* vbase = &Vb[g * 8 + (lane & 7)][quad * 8];

        #pragma unroll
        for (int kt = 0; kt < 3; ++kt) {
            // K block for this kt: 8 b128 broadcast reads, reused across 6 m-tiles
            v4f kA[4], kB[4];
            #pragma unroll
            for (int c = 0; c < 4; ++c) {
                kA[c] = *reinterpret_cast<const v4f*>(kbase + c * 96 + kt * 32);
                kB[c] = *reinterpret_cast<const v4f*>(kbase + c * 96 + kt * 32 + 4);
            }
            v8s vf = *reinterpret_cast<const v8s*>(vbase + kt * 32);

            #pragma unroll
            for (int mt = 0; mt < 6; ++mt) {
                // vector form: backend selects v_pk_fma_f32
                v4f sA = (v4f)(qv[0][mt]) * kA[0];
                v4f sB = (v4f)(qv[0][mt]) * kB[0];
                #pragma unroll
                for (int c = 1; c < 4; ++c) {
                    sA += (v4f)(qv[c][mt]) * kA[c];
                    sB += (v4f)(qv[c][mt]) * kB[c];
                }
                v4f eA, eB;
                #pragma unroll
                for (int jj = 0; jj < 4; ++jj) {
                    eA[jj] = __builtin_amdgcn_exp2f(sA[jj]);
                    eB[jj] = __builtin_amdgcn_exp2f(sB[jj]);
                }
                rs4[mt] += eA + eB;
                union { unsigned u[4]; v8s v; } pf;
                pf.u[0] = cvt_pk_bf16(eA[0], eA[1]);
                pf.u[1] = cvt_pk_bf16(eA[2], eA[3]);
                pf.u[2] = cvt_pk_bf16(eB[0], eB[1]);
                pf.u[3] = cvt_pk_bf16(eB[2], eB[3]);
                acc[mt] = __builtin_amdgcn_mfma_f32_16x16x32_bf16(pf.v, vf, acc[mt], 0, 0, 0);
            }
        }

        // row denominators: horizontal + reduce across the 4 quads
        float zr[6];
        #pragma unroll
        for (int mt = 0; mt < 6; ++mt) {
            float t = (rs4[mt][0] + rs4[mt][1]) + (rs4[mt][2] + rs4[mt][3]);
            t += __shfl_xor(t, 16);
            t += __shfl_xor(t, 32);
            zr[mt] = __builtin_amdgcn_rcpf(t);
        }

        const int dd = g * 8 + (r15 & 7);
        float osc = out_gamma[dd] * rsqrtf(out_var[dd] + EPS);
        float ob  = out_beta[dd] - out_mean[dd] * osc;

        #pragma unroll
        for (int mt = 0; mt < 6; ++mt) {
            float zz[4];
            #pragma unroll
            for (int reg = 0; reg < 4; ++reg)         // all lanes active for shfl
                zz[reg] = __shfl(zr[mt], quad * 4 + reg);
            if (r15 < 8) {
                float4 o4;
                o4.x = acc[mt][0] * (zz[0] * osc) + ob;
                o4.y = acc[mt][1] * (zz[1] * osc) + ob;
                o4.z = acc[mt][2] * (zz[2] * osc) + ob;
                o4.w = acc[mt][3] * (zz[3] * osc) + ob;
                // direct final-layout store: out[nt][cl][dd][hs], cl = mt*16+quad*4+reg
                const size_t base = (size_t)nt * 393216 + (size_t)dd * 64 + hs;
                dst[base + (size_t)(mt * 16 + quad * 4 + 0) * 4096] = o4.x;
                dst[base + (size_t)(mt * 16 + quad * 4 + 1) * 4096] = o4.y;
                dst[base + (size_t)(mt * 16 + quad * 4 + 2) * 4096] = o4.z;
                dst[base + (size_t)(mt * 16 + quad * 4 + 3) * 4096] = o4.w;
            }
        }
    }
}

extern "C" void kernel_launch(void* const* d_in, const int* in_sizes, int n_in,
                              void* d_out, int out_size, void* d_ws, size_t ws_size,
                              hipStream_t stream) {
    const float* x         = (const float*)d_in[0];
    const float* w_qkv     = (const float*)d_in[1];
    const float* qkv_gamma = (const float*)d_in[2];
    const float* qkv_beta  = (const float*)d_in[3];
    const float* qkv_mean  = (const float*)d_in[4];
    const float* qkv_var   = (const float*)d_in[5];
    const float* sim_gamma = (const float*)d_in[6];
    const float* sim_beta  = (const float*)d_in[7];
    const float* sim_mean  = (const float*)d_in[8];
    const float* sim_var   = (const float*)d_in[9];
    const float* out_gamma = (const float*)d_in[10];
    const float* out_beta  = (const float*)d_in[11];
    const float* out_mean  = (const float*)d_in[12];
    const float* out_var   = (const float*)d_in[13];
    float* out = (float*)d_out;

    attn_kernel<<<2048, 256, 0, stream>>>(
        x, w_qkv, qkv_gamma, qkv_beta, qkv_mean, qkv_var,
        sim_gamma, sim_beta, sim_mean, sim_var,
        out_gamma, out_beta, out_mean, out_var, out);
}

// Round 9
// 163.877 us; speedup vs baseline: 1.0983x; 1.0983x over previous
//
#include <hip/hip_runtime.h>

#define EPS 1e-5f
#define LOG2E 1.4426950408889634f

typedef short v8s __attribute__((ext_vector_type(8)));
typedef float v4f __attribute__((ext_vector_type(4)));

// RNE f32->bf16 pair pack: single instruction, HW-verified pattern (learn_hip m240/T12)
__device__ inline unsigned cvt_pk_bf16(float a, float b) {
    unsigned r;
    asm("v_cvt_pk_bf16_f32 %0, %1, %2" : "=v"(r) : "v"(a), "v"(b));
    return r;
}
__device__ inline unsigned short f2bf(float f) {
    return (unsigned short)cvt_pk_bf16(f, f);
}
__device__ inline float bf2f(unsigned short u) {
    union { unsigned u; float f; } v; v.u = (unsigned)u << 16;
    return v.f;
}

// LDS map (38,912 B) — R4 layout (best measured attn core, 57.0 us):
//   [0      .. 25600)  QKf  float[64][100]   rows g*8+{0..3}=Q~ (pre-scaled by simA*log2e), g*8+{4..7}=K
//   [25600  .. 38912)  Vb   ushort[64][104]  V bf16 rows g*8+c
//   phase-1 overlay: Xb ushort[96][72] @0, Wb ushort[128][72] @13824 (dead before epilogue)
//
// Phase 2 is BARRIER-FREE: wave w owns groups {2w, 2w+1}, whose QKf/Vb rows
// were written by wave w itself in the phase-1 epilogue. Score lane layout ==
// MFMA A-fragment layout, so P never leaves registers.
// R9: ws intermediate is bf16 (uint2 of 4 bf16) — halves attn write traffic
// and transpose read traffic. DIRECT fallback stays f32.
// NOTE: __launch_bounds__ min-waves/EU must stay <=3 (R5/R6 corruption bisect).
template<bool DIRECT>
__global__ __launch_bounds__(256, 3) void attn_kernel(
    const float* __restrict__ x,
    const float* __restrict__ w,
    const float* __restrict__ qkv_gamma, const float* __restrict__ qkv_beta,
    const float* __restrict__ qkv_mean,  const float* __restrict__ qkv_var,
    const float* __restrict__ sim_gamma, const float* __restrict__ sim_beta,
    const float* __restrict__ sim_mean,  const float* __restrict__ sim_var,
    const float* __restrict__ out_gamma, const float* __restrict__ out_beta,
    const float* __restrict__ out_mean,  const float* __restrict__ out_var,
    float* __restrict__ dst)
{
    __shared__ __align__(16) unsigned char smem[38912];
    float (*QKf)[100]         = (float(*)[100])smem;
    unsigned short (*Vb)[104] = (unsigned short(*)[104])(smem + 25600);
    unsigned short (*Xb)[72]  = (unsigned short(*)[72])smem;
    unsigned short (*Wb)[72]  = (unsigned short(*)[72])(smem + 13824);

    const int tid  = threadIdx.x;
    const int lane = tid & 63;
    const int wid  = tid >> 6;
    const int quad = lane >> 4;
    const int b  = blockIdx.x;          // b = nt*64 + hs
    const int nt = b >> 6;
    const int hs = b & 63;

    const float* xb = x + (size_t)nt * 393216 + (size_t)hs * 64;
    const float4* x4 = reinterpret_cast<const float4*>(xb);
    const float4* w4 = reinterpret_cast<const float4*>(w);

    // ---------------- Phase 1a: stage X, W as bf16 ----------------
    #pragma unroll
    for (int it = 0; it < 6; ++it) {
        int idx = tid + it * 256;               // 1536 float4s
        int cl = idx >> 4, v = idx & 15;
        float4 val = x4[cl * 1024 + v];
        unsigned* dx = (unsigned*)&Xb[cl][v * 4];
        dx[0] = cvt_pk_bf16(val.x, val.y);
        dx[1] = cvt_pk_bf16(val.z, val.w);
    }
    #pragma unroll
    for (int it = 0; it < 8; ++it) {
        int idx = tid + it * 256;               // 2048 float4s
        int r = idx >> 4, v = idx & 15;
        float4 val = w4[r * 16 + v];
        unsigned* dw = (unsigned*)&Wb[r][v * 4];
        dw[0] = cvt_pk_bf16(val.x, val.y);
        dw[1] = cvt_pk_bf16(val.z, val.w);
    }
    __syncthreads();

    // ---------------- Phase 1b: QKV = W @ X via MFMA ----------------
    v4f acc1[2][6];
    #pragma unroll
    for (int mi = 0; mi < 2; ++mi)
        #pragma unroll
        for (int ni = 0; ni < 6; ++ni) acc1[mi][ni] = (v4f)(0.f);

    #pragma unroll
    for (int kt = 0; kt < 2; ++kt) {
        v8s a0 = *reinterpret_cast<const v8s*>(&Wb[(wid * 2 + 0) * 16 + (lane & 15)][kt * 32 + quad * 8]);
        v8s a1 = *reinterpret_cast<const v8s*>(&Wb[(wid * 2 + 1) * 16 + (lane & 15)][kt * 32 + quad * 8]);
        #pragma unroll
        for (int ni = 0; ni < 6; ++ni) {
            v8s bfr = *reinterpret_cast<const v8s*>(&Xb[ni * 16 + (lane & 15)][kt * 32 + quad * 8]);
            acc1[0][ni] = __builtin_amdgcn_mfma_f32_16x16x32_bf16(a0, bfr, acc1[0][ni], 0, 0, 0);
            acc1[1][ni] = __builtin_amdgcn_mfma_f32_16x16x32_bf16(a1, bfr, acc1[1][ni], 0, 0, 0);
        }
    }
    __syncthreads();    // staging dead; region becomes QKf/Vb (last barrier in kernel)

    // epilogue: BN; rows r<8 of each 16 -> QKf fp32 (Q rows scaled by simA*log2e); r>=8 -> Vb bf16
    #pragma unroll
    for (int mi = 0; mi < 2; ++mi) {
        const int mt = wid * 2 + mi;            // = group g
        const float sA = sim_gamma[mt] * rsqrtf(sim_var[mt] + EPS) * LOG2E;
        #pragma unroll
        for (int reg = 0; reg < 4; ++reg) {
            int o = mt * 16 + quad * 4 + reg;
            int r = o & 15;
            float sc = qkv_gamma[o] * rsqrtf(qkv_var[o] + EPS);
            float mb = qkv_beta[o] - qkv_mean[o] * sc;
            if (r < 4) { sc *= sA; mb *= sA; }
            if (r < 8) {
                #pragma unroll
                for (int ni = 0; ni < 6; ++ni)
                    QKf[mt * 8 + r][ni * 16 + (lane & 15)] = acc1[mi][ni][reg] * sc + mb;
            } else {
                #pragma unroll
                for (int ni = 0; ni < 6; ++ni)
                    Vb[mt * 8 + (r - 8)][ni * 16 + (lane & 15)] = f2bf(acc1[mi][ni][reg] * sc + mb);
            }
        }
    }
    // NO barrier: each wave consumes only rows it just wrote.

    // ---------------- Phase 2: wave-private groups, P in registers ----------------
    const int r15 = lane & 15;

    for (int gi = 0; gi < 2; ++gi) {
        const int g = wid * 2 + gi;

        // q preload: 24 broadcast b32 reads
        float qv[4][6];
        #pragma unroll
        for (int c = 0; c < 4; ++c)
            #pragma unroll
            for (int mt = 0; mt < 6; ++mt)
                qv[c][mt] = QKf[g * 8 + c][mt * 16 + r15];

        v4f acc[6];
        v4f rs4[6];
        #pragma unroll
        for (int mt = 0; mt < 6; ++mt) { acc[mt] = (v4f)(0.f); rs4[mt] = (v4f)(0.f); }

        const float* kbase = &QKf[g * 8 + 4][quad * 8];
        const unsigned short* vbase = &Vb[g * 8 + (lane & 7)][quad * 8];

        #pragma unroll
        for (int kt = 0; kt < 3; ++kt) {
            // K block for this kt: 8 b128 broadcast reads, reused across 6 m-tiles
            v4f kA[4], kB[4];
            #pragma unroll
            for (int c = 0; c < 4; ++c) {
                kA[c] = *reinterpret_cast<const v4f*>(kbase + c * 100 + kt * 32);
                kB[c] = *reinterpret_cast<const v4f*>(kbase + c * 100 + kt * 32 + 4);
            }
            v8s vf = *reinterpret_cast<const v8s*>(vbase + kt * 32);

            #pragma unroll
            for (int mt = 0; mt < 6; ++mt) {
                // vector form: backend selects v_pk_fma_f32
                v4f sA = (v4f)(qv[0][mt]) * kA[0];
                v4f sB = (v4f)(qv[0][mt]) * kB[0];
                #pragma unroll
                for (int c = 1; c < 4; ++c) {
                    sA += (v4f)(qv[c][mt]) * kA[c];
                    sB += (v4f)(qv[c][mt]) * kB[c];
                }
                v4f eA, eB;
                #pragma unroll
                for (int jj = 0; jj < 4; ++jj) {
                    eA[jj] = __builtin_amdgcn_exp2f(sA[jj]);
                    eB[jj] = __builtin_amdgcn_exp2f(sB[jj]);
                }
                rs4[mt] += eA + eB;
                union { unsigned u[4]; v8s v; } pf;
                pf.u[0] = cvt_pk_bf16(eA[0], eA[1]);
                pf.u[1] = cvt_pk_bf16(eA[2], eA[3]);
                pf.u[2] = cvt_pk_bf16(eB[0], eB[1]);
                pf.u[3] = cvt_pk_bf16(eB[2], eB[3]);
                acc[mt] = __builtin_amdgcn_mfma_f32_16x16x32_bf16(pf.v, vf, acc[mt], 0, 0, 0);
            }
        }

        // row denominators: horizontal + reduce across the 4 quads
        float zr[6];
        #pragma unroll
        for (int mt = 0; mt < 6; ++mt) {
            float t = (rs4[mt][0] + rs4[mt][1]) + (rs4[mt][2] + rs4[mt][3]);
            t += __shfl_xor(t, 16);
            t += __shfl_xor(t, 32);
            zr[mt] = __builtin_amdgcn_rcpf(t);
        }

        const int dd = g * 8 + (r15 & 7);
        float osc = out_gamma[dd] * rsqrtf(out_var[dd] + EPS);
        float ob  = out_beta[dd] - out_mean[dd] * osc;

        #pragma unroll
        for (int mt = 0; mt < 6; ++mt) {
            float zz[4];
            #pragma unroll
            for (int reg = 0; reg < 4; ++reg)         // all lanes active for shfl
                zz[reg] = __shfl(zr[mt], quad * 4 + reg);
            if (r15 < 8) {
                float4 o4;
                o4.x = acc[mt][0] * (zz[0] * osc) + ob;
                o4.y = acc[mt][1] * (zz[1] * osc) + ob;
                o4.z = acc[mt][2] * (zz[2] * osc) + ob;
                o4.w = acc[mt][3] * (zz[3] * osc) + ob;
                if (DIRECT) {
                    const size_t base = (size_t)nt * 393216 + (size_t)dd * 64 + hs;
                    dst[base + (size_t)(mt * 16 + quad * 4 + 0) * 4096] = o4.x;
                    dst[base + (size_t)(mt * 16 + quad * 4 + 1) * 4096] = o4.y;
                    dst[base + (size_t)(mt * 16 + quad * 4 + 2) * 4096] = o4.z;
                    dst[base + (size_t)(mt * 16 + quad * 4 + 3) * 4096] = o4.w;
                } else {
                    // ws_bf16[b][dd][cl-pack]: uint2 = 4 bf16 of consecutive cl
                    uint2 pkd;
                    pkd.x = cvt_pk_bf16(o4.x, o4.y);
                    pkd.y = cvt_pk_bf16(o4.z, o4.w);
                    reinterpret_cast<uint2*>(dst)[(size_t)b * 1536 + dd * 24 + mt * 4 + quad] = pkd;
                }
            }
        }
    }
}

// ws_bf16 (nt, hs, D, cl-pack) -> out f32 (nt, cl, D, hs); block = (nt, D); 2048 blocks
__global__ __launch_bounds__(256) void transpose_kernel(const float* __restrict__ ws,
                                                        float* __restrict__ out)
{
    __shared__ float tile[64][97];
    const int blk = blockIdx.x;          // nt*64 + D
    const int nt = blk >> 6, D = blk & 63;
    const uint2* wsu = reinterpret_cast<const uint2*>(ws);
    v4f* out4 = reinterpret_cast<v4f*>(out);

    #pragma unroll
    for (int it = 0; it < 6; ++it) {
        int idx = threadIdx.x + it * 256;       // 1536 uint2 = 64 hs x 24 c4
        int hsr = idx / 24, c4 = idx - hsr * 24;
        uint2 v = wsu[(size_t)nt * 98304 + (size_t)hsr * 1536 + D * 24 + c4];
        tile[hsr][c4 * 4 + 0] = bf2f((unsigned short)(v.x));
        tile[hsr][c4 * 4 + 1] = bf2f((unsigned short)(v.x >> 16));
        tile[hsr][c4 * 4 + 2] = bf2f((unsigned short)(v.y));
        tile[hsr][c4 * 4 + 3] = bf2f((unsigned short)(v.y >> 16));
    }
    __syncthreads();

    #pragma unroll
    for (int it = 0; it < 6; ++it) {
        int idx = threadIdx.x + it * 256;       // 1536 float4s = 96 cl x 16 h4
        int cl = idx >> 4, h4 = idx & 15;
        v4f v;
        v[0] = tile[h4 * 4 + 0][cl];
        v[1] = tile[h4 * 4 + 1][cl];
        v[2] = tile[h4 * 4 + 2][cl];
        v[3] = tile[h4 * 4 + 3][cl];
        __builtin_nontemporal_store(v, &out4[(size_t)nt * 98304 + (size_t)cl * 1024 + D * 16 + h4]);
    }
}

extern "C" void kernel_launch(void* const* d_in, const int* in_sizes, int n_in,
                              void* d_out, int out_size, void* d_ws, size_t ws_size,
                              hipStream_t stream) {
    const float* x         = (const float*)d_in[0];
    const float* w_qkv     = (const float*)d_in[1];
    const float* qkv_gamma = (const float*)d_in[2];
    const float* qkv_beta  = (const float*)d_in[3];
    const float* qkv_mean  = (const float*)d_in[4];
    const float* qkv_var   = (const float*)d_in[5];
    const float* sim_gamma = (const float*)d_in[6];
    const float* sim_beta  = (const float*)d_in[7];
    const float* sim_mean  = (const float*)d_in[8];
    const float* sim_var   = (const float*)d_in[9];
    const float* out_gamma = (const float*)d_in[10];
    const float* out_beta  = (const float*)d_in[11];
    const float* out_mean  = (const float*)d_in[12];
    const float* out_var   = (const float*)d_in[13];
    float* out = (float*)d_out;

    const size_t ws_need = (size_t)2048 * 1536 * sizeof(uint2);  // 25.2 MB bf16 ws

    if (ws_size >= ws_need) {
        float* wsb = (float*)d_ws;
        attn_kernel<false><<<2048, 256, 0, stream>>>(
            x, w_qkv, qkv_gamma, qkv_beta, qkv_mean, qkv_var,
            sim_gamma, sim_beta, sim_mean, sim_var,
            out_gamma, out_beta, out_mean, out_var, wsb);
        transpose_kernel<<<2048, 256, 0, stream>>>(wsb, out);
    } else {
        attn_kernel<true><<<2048, 256, 0, stream>>>(
            x, w_qkv, qkv_gamma, qkv_beta, qkv_mean, qkv_var,
            sim_gamma, sim_beta, sim_mean, sim_var,
            out_gamma, out_beta, out_mean, out_var, out);
    }
}

// Round 12
// 163.309 us; speedup vs baseline: 1.1021x; 1.0035x over previous
//
#include <hip/hip_runtime.h>

#define EPS 1e-5f
#define LOG2E 1.4426950408889634f

typedef short v8s __attribute__((ext_vector_type(8)));
typedef float v4f __attribute__((ext_vector_type(4)));

// RNE f32->bf16 pair pack: single instruction, HW-verified pattern (learn_hip m240/T12)
__device__ inline unsigned cvt_pk_bf16(float a, float b) {
    unsigned r;
    asm("v_cvt_pk_bf16_f32 %0, %1, %2" : "=v"(r) : "v"(a), "v"(b));
    return r;
}
__device__ inline unsigned short f2bf(float f) {
    return (unsigned short)cvt_pk_bf16(f, f);
}
__device__ inline float bf2f(unsigned short u) {
    union { unsigned u; float f; } v; v.u = (unsigned)u << 16;
    return v.f;
}

// LDS map (38,912 B) — R4/R9 layout (best measured attn core):
//   [0      .. 25600)  QKf  float[64][100]   rows g*8+{0..3}=Q~ (pre-scaled by simA*log2e), g*8+{4..7}=K
//   [25600  .. 38912)  Vb   ushort[64][104]  V bf16 rows g*8+c
//   phase-1 overlay: Xb ushort[96][72] @0, Wb ushort[128][72] @13824 (dead before epilogue)
//
// Phase 2 is BARRIER-FREE: wave w owns groups {2w, 2w+1}, whose QKf/Vb rows
// were written by wave w itself in the phase-1 epilogue. Score lane layout ==
// MFMA A-fragment layout, so P never leaves registers.
// ws intermediate is bf16 (uint2 of 4 bf16) — halves attn write traffic and
// transpose read traffic. DIRECT fallback stays f32.
// SESSION LEDGER:
//  - __launch_bounds__ min-waves/EU > 3 forces VGPR cap < liveness -> silent
//    corruption (R5/R6, bisected R7). Keep (256,3).
//  - 8-wave/512-thread restructure (1 group/wave) NaNs even with full barrier
//    fencing and default launch_bounds (R10/R11) -- abandoned.
//  - XCD-chunked DIRECT scatter store: write-combining works (no amplification)
//    but scatter issue cost dominates, attn 57->89 us (R8) -- abandoned.
template<bool DIRECT>
__global__ __launch_bounds__(256, 3) void attn_kernel(
    const float* __restrict__ x,
    const float* __restrict__ w,
    const float* __restrict__ qkv_gamma, const float* __restrict__ qkv_beta,
    const float* __restrict__ qkv_mean,  const float* __restrict__ qkv_var,
    const float* __restrict__ sim_gamma, const float* __restrict__ sim_beta,
    const float* __restrict__ sim_mean,  const float* __restrict__ sim_var,
    const float* __restrict__ out_gamma, const float* __restrict__ out_beta,
    const float* __restrict__ out_mean,  const float* __restrict__ out_var,
    float* __restrict__ dst)
{
    __shared__ __align__(16) unsigned char smem[38912];
    float (*QKf)[100]         = (float(*)[100])smem;
    unsigned short (*Vb)[104] = (unsigned short(*)[104])(smem + 25600);
    unsigned short (*Xb)[72]  = (unsigned short(*)[72])smem;
    unsigned short (*Wb)[72]  = (unsigned short(*)[72])(smem + 13824);

    const int tid  = threadIdx.x;
    const int lane = tid & 63;
    const int wid  = tid >> 6;
    const int quad = lane >> 4;
    const int b  = blockIdx.x;          // b = nt*64 + hs
    const int nt = b >> 6;
    const int hs = b & 63;

    const float* xb = x + (size_t)nt * 393216 + (size_t)hs * 64;
    const float4* x4 = reinterpret_cast<const float4*>(xb);
    const float4* w4 = reinterpret_cast<const float4*>(w);

    // ---------------- Phase 1a: stage X, W as bf16 ----------------
    #pragma unroll
    for (int it = 0; it < 6; ++it) {
        int idx = tid + it * 256;               // 1536 float4s
        int cl = idx >> 4, v = idx & 15;
        float4 val = x4[cl * 1024 + v];
        unsigned* dx = (unsigned*)&Xb[cl][v * 4];
        dx[0] = cvt_pk_bf16(val.x, val.y);
        dx[1] = cvt_pk_bf16(val.z, val.w);
    }
    #pragma unroll
    for (int it = 0; it < 8; ++it) {
        int idx = tid + it * 256;               // 2048 float4s
        int r = idx >> 4, v = idx & 15;
        float4 val = w4[r * 16 + v];
        unsigned* dw = (unsigned*)&Wb[r][v * 4];
        dw[0] = cvt_pk_bf16(val.x, val.y);
        dw[1] = cvt_pk_bf16(val.z, val.w);
    }
    __syncthreads();

    // ---------------- Phase 1b: QKV = W @ X via MFMA ----------------
    v4f acc1[2][6];
    #pragma unroll
    for (int mi = 0; mi < 2; ++mi)
        #pragma unroll
        for (int ni = 0; ni < 6; ++ni) acc1[mi][ni] = (v4f)(0.f);

    #pragma unroll
    for (int kt = 0; kt < 2; ++kt) {
        v8s a0 = *reinterpret_cast<const v8s*>(&Wb[(wid * 2 + 0) * 16 + (lane & 15)][kt * 32 + quad * 8]);
        v8s a1 = *reinterpret_cast<const v8s*>(&Wb[(wid * 2 + 1) * 16 + (lane & 15)][kt * 32 + quad * 8]);
        #pragma unroll
        for (int ni = 0; ni < 6; ++ni) {
            v8s bfr = *reinterpret_cast<const v8s*>(&Xb[ni * 16 + (lane & 15)][kt * 32 + quad * 8]);
            acc1[0][ni] = __builtin_amdgcn_mfma_f32_16x16x32_bf16(a0, bfr, acc1[0][ni], 0, 0, 0);
            acc1[1][ni] = __builtin_amdgcn_mfma_f32_16x16x32_bf16(a1, bfr, acc1[1][ni], 0, 0, 0);
        }
    }
    __syncthreads();    // staging dead; region becomes QKf/Vb (last barrier in kernel)

    // epilogue: BN; rows r<8 of each 16 -> QKf fp32 (Q rows scaled by simA*log2e); r>=8 -> Vb bf16
    #pragma unroll
    for (int mi = 0; mi < 2; ++mi) {
        const int mt = wid * 2 + mi;            // = group g
        const float sA = sim_gamma[mt] * rsqrtf(sim_var[mt] + EPS) * LOG2E;
        #pragma unroll
        for (int reg = 0; reg < 4; ++reg) {
            int o = mt * 16 + quad * 4 + reg;
            int r = o & 15;
            float sc = qkv_gamma[o] * rsqrtf(qkv_var[o] + EPS);
            float mb = qkv_beta[o] - qkv_mean[o] * sc;
            if (r < 4) { sc *= sA; mb *= sA; }
            if (r < 8) {
                #pragma unroll
                for (int ni = 0; ni < 6; ++ni)
                    QKf[mt * 8 + r][ni * 16 + (lane & 15)] = acc1[mi][ni][reg] * sc + mb;
            } else {
                #pragma unroll
                for (int ni = 0; ni < 6; ++ni)
                    Vb[mt * 8 + (r - 8)][ni * 16 + (lane & 15)] = f2bf(acc1[mi][ni][reg] * sc + mb);
            }
        }
    }
    // NO barrier: each wave consumes only rows it just wrote.

    // ---------------- Phase 2: wave-private groups, P in registers ----------------
    const int r15 = lane & 15;

    for (int gi = 0; gi < 2; ++gi) {
        const int g = wid * 2 + gi;

        // q preload: 24 broadcast b32 reads
        float qv[4][6];
        #pragma unroll
        for (int c = 0; c < 4; ++c)
            #pragma unroll
            for (int mt = 0; mt < 6; ++mt)
                qv[c][mt] = QKf[g * 8 + c][mt * 16 + r15];

        v4f acc[6];
        v4f rs4[6];
        #pragma unroll
        for (int mt = 0; mt < 6; ++mt) { acc[mt] = (v4f)(0.f); rs4[mt] = (v4f)(0.f); }

        const float* kbase = &QKf[g * 8 + 4][quad * 8];
        const unsigned short* vbase = &Vb[g * 8 + (lane & 7)][quad * 8];

        #pragma unroll
        for (int kt = 0; kt < 3; ++kt) {
            // K block for this kt: 8 b128 broadcast reads, reused across 6 m-tiles
            v4f kA[4], kB[4];
            #pragma unroll
            for (int c = 0; c < 4; ++c) {
                kA[c] = *reinterpret_cast<const v4f*>(kbase + c * 100 + kt * 32);
                kB[c] = *reinterpret_cast<const v4f*>(kbase + c * 100 + kt * 32 + 4);
            }
            v8s vf = *reinterpret_cast<const v8s*>(vbase + kt * 32);

            #pragma unroll
            for (int mt = 0; mt < 6; ++mt) {
                // vector form: backend selects v_pk_fma_f32
                v4f sA = (v4f)(qv[0][mt]) * kA[0];
                v4f sB = (v4f)(qv[0][mt]) * kB[0];
                #pragma unroll
                for (int c = 1; c < 4; ++c) {
                    sA += (v4f)(qv[c][mt]) * kA[c];
                    sB += (v4f)(qv[c][mt]) * kB[c];
                }
                v4f eA, eB;
                #pragma unroll
                for (int jj = 0; jj < 4; ++jj) {
                    eA[jj] = __builtin_amdgcn_exp2f(sA[jj]);
                    eB[jj] = __builtin_amdgcn_exp2f(sB[jj]);
                }
                rs4[mt] += eA + eB;
                union { unsigned u[4]; v8s v; } pf;
                pf.u[0] = cvt_pk_bf16(eA[0], eA[1]);
                pf.u[1] = cvt_pk_bf16(eA[2], eA[3]);
                pf.u[2] = cvt_pk_bf16(eB[0], eB[1]);
                pf.u[3] = cvt_pk_bf16(eB[2], eB[3]);
                acc[mt] = __builtin_amdgcn_mfma_f32_16x16x32_bf16(pf.v, vf, acc[mt], 0, 0, 0);
            }
        }

        // row denominators: horizontal + reduce across the 4 quads
        float zr[6];
        #pragma unroll
        for (int mt = 0; mt < 6; ++mt) {
            float t = (rs4[mt][0] + rs4[mt][1]) + (rs4[mt][2] + rs4[mt][3]);
            t += __shfl_xor(t, 16);
            t += __shfl_xor(t, 32);
            zr[mt] = __builtin_amdgcn_rcpf(t);
        }

        const int dd = g * 8 + (r15 & 7);
        float osc = out_gamma[dd] * rsqrtf(out_var[dd] + EPS);
        float ob  = out_beta[dd] - out_mean[dd] * osc;

        #pragma unroll
        for (int mt = 0; mt < 6; ++mt) {
            float zz[4];
            #pragma unroll
            for (int reg = 0; reg < 4; ++reg)         // all lanes active for shfl
                zz[reg] = __shfl(zr[mt], quad * 4 + reg);
            if (r15 < 8) {
                float4 o4;
                o4.x = acc[mt][0] * (zz[0] * osc) + ob;
                o4.y = acc[mt][1] * (zz[1] * osc) + ob;
                o4.z = acc[mt][2] * (zz[2] * osc) + ob;
                o4.w = acc[mt][3] * (zz[3] * osc) + ob;
                if (DIRECT) {
                    const size_t base = (size_t)nt * 393216 + (size_t)dd * 64 + hs;
                    dst[base + (size_t)(mt * 16 + quad * 4 + 0) * 4096] = o4.x;
                    dst[base + (size_t)(mt * 16 + quad * 4 + 1) * 4096] = o4.y;
                    dst[base + (size_t)(mt * 16 + quad * 4 + 2) * 4096] = o4.z;
                    dst[base + (size_t)(mt * 16 + quad * 4 + 3) * 4096] = o4.w;
                } else {
                    // ws_bf16[b][dd][cl-pack]: uint2 = 4 bf16 of consecutive cl
                    uint2 pkd;
                    pkd.x = cvt_pk_bf16(o4.x, o4.y);
                    pkd.y = cvt_pk_bf16(o4.z, o4.w);
                    reinterpret_cast<uint2*>(dst)[(size_t)b * 1536 + dd * 24 + mt * 4 + quad] = pkd;
                }
            }
        }
    }
}

// ws_bf16 (nt, hs, D, cl-pack) -> out f32 (nt, cl, D, hs); block = (nt, D); 2048 blocks
__global__ __launch_bounds__(256) void transpose_kernel(const float* __restrict__ ws,
                                                        float* __restrict__ out)
{
    __shared__ float tile[64][97];
    const int blk = blockIdx.x;          // nt*64 + D
    const int nt = blk >> 6, D = blk & 63;
    const uint2* wsu = reinterpret_cast<const uint2*>(ws);
    v4f* out4 = reinterpret_cast<v4f*>(out);

    #pragma unroll
    for (int it = 0; it < 6; ++it) {
        int idx = threadIdx.x + it * 256;       // 1536 uint2 = 64 hs x 24 c4
        int hsr = idx / 24, c4 = idx - hsr * 24;
        uint2 v = wsu[(size_t)nt * 98304 + (size_t)hsr * 1536 + D * 24 + c4];
        tile[hsr][c4 * 4 + 0] = bf2f((unsigned short)(v.x));
        tile[hsr][c4 * 4 + 1] = bf2f((unsigned short)(v.x >> 16));
        tile[hsr][c4 * 4 + 2] = bf2f((unsigned short)(v.y));
        tile[hsr][c4 * 4 + 3] = bf2f((unsigned short)(v.y >> 16));
    }
    __syncthreads();

    #pragma unroll
    for (int it = 0; it < 6; ++it) {
        int idx = threadIdx.x + it * 256;       // 1536 float4s = 96 cl x 16 h4
        int cl = idx >> 4, h4 = idx & 15;
        v4f v;
        v[0] = tile[h4 * 4 + 0][cl];
        v[1] = tile[h4 * 4 + 1][cl];
        v[2] = tile[h4 * 4 + 2][cl];
        v[3] = tile[h4 * 4 + 3][cl];
        __builtin_nontemporal_store(v, &out4[(size_t)nt * 98304 + (size_t)cl * 1024 + D * 16 + h4]);
    }
}

extern "C" void kernel_launch(void* const* d_in, const int* in_sizes, int n_in,
                              void* d_out, int out_size, void* d_ws, size_t ws_size,
                              hipStream_t stream) {
    const float* x         = (const float*)d_in[0];
    const float* w_qkv     = (const float*)d_in[1];
    const float* qkv_gamma = (const float*)d_in[2];
    const float* qkv_beta  = (const float*)d_in[3];
    const float* qkv_mean  = (const float*)d_in[4];
    const float* qkv_var   = (const float*)d_in[5];
    const float* sim_gamma = (const float*)d_in[6];
    const float* sim_beta  = (const float*)d_in[7];
    const float* sim_mean  = (const float*)d_in[8];
    const float* sim_var   = (const float*)d_in[9];
    const float* out_gamma = (const float*)d_in[10];
    const float* out_beta  = (const float*)d_in[11];
    const float* out_mean  = (const float*)d_in[12];
    const float* out_var   = (const float*)d_in[13];
    float* out = (float*)d_out;

    const size_t ws_need = (size_t)2048 * 1536 * sizeof(uint2);  // 25.2 MB bf16 ws

    if (ws_size >= ws_need) {
        float* wsb = (float*)d_ws;
        attn_kernel<false><<<2048, 256, 0, stream>>>(
            x, w_qkv, qkv_gamma, qkv_beta, qkv_mean, qkv_var,
            sim_gamma, sim_beta, sim_mean, sim_var,
            out_gamma, out_beta, out_mean, out_var, wsb);
        transpose_kernel<<<2048, 256, 0, stream>>>(wsb, out);
    } else {
        attn_kernel<true><<<2048, 256, 0, stream>>>(
            x, w_qkv, qkv_gamma, qkv_beta, qkv_mean, qkv_var,
            sim_gamma, sim_beta, sim_mean, sim_var,
            out_gamma, out_beta, out_mean, out_var, out);
    }
}